// Round 2
// baseline (360.153 us; speedup 1.0000x reference)
//
#include <hip/hip_runtime.h>

// Problem constants
static constexpr int   Cc  = 21;
static constexpr int   HWn = 512 * 512;         // 262144 = 2^18
static constexpr int   Nn  = 8 * HWn;           // 2097152 pixels
static constexpr float MAXM = 0.5f;
static constexpr float Sc   = 30.0f;

// ws layout (bytes): 0: int counts[21] ; 96: double acc ; 104: int done
// All zeroed by one 256-byte memsetAsync.
static constexpr int WS_COUNTS = 0;
static constexpr int WS_ACC    = 96;
static constexpr int WS_DONE   = 104;

// ---------------------------------------------------------------------------
// K1: class histogram. One int4 (4 labels) per thread, LDS-local atomics,
// then 21 global atomics per block.
__global__ __launch_bounds__(256) void hist_kernel(const int4* __restrict__ t4,
                                                   int* __restrict__ counts) {
    __shared__ int lh[Cc];
    int t = threadIdx.x;
    if (t < Cc) lh[t] = 0;
    __syncthreads();
    int tid = blockIdx.x * 256 + t;           // tid in [0, Nn/4)
    int4 v = t4[tid];
    atomicAdd(&lh[v.x], 1);
    atomicAdd(&lh[v.y], 1);
    atomicAdd(&lh[v.z], 1);
    atomicAdd(&lh[v.w], 1);
    __syncthreads();
    if (t < Cc) atomicAdd(&counts[t], lh[t]);
}

// ---------------------------------------------------------------------------
// K2: fused m_list + loss + finalize.
//  - each block recomputes sm[c] = S * m_list[c] from global counts (cheap)
//  - online logsumexp over the 21 classes, 4 pixels/thread via float4 loads
//  - block reduce -> one double atomicAdd -> last block writes the mean
__global__ __launch_bounds__(256) void loss_kernel(const float* __restrict__ pred,
                                                   const int4* __restrict__ t4,
                                                   const int* __restrict__ counts,
                                                   double* __restrict__ acc,
                                                   int* __restrict__ done,
                                                   float* __restrict__ out) {
    __shared__ float s_sm[Cc];   // m_list values (unscaled)
    __shared__ float wsum[4];

    int t = threadIdx.x;
    if (t < Cc) s_sm[t] = 1.0f / sqrtf(sqrtf((float)counts[t] + 1e-4f));
    __syncthreads();

    // every thread computes the max itself (broadcast LDS reads, no races)
    float mxm = s_sm[0];
    #pragma unroll
    for (int i = 1; i < Cc; ++i) mxm = fmaxf(mxm, s_sm[i]);
    float scl = Sc * (MAXM / mxm);            // sm[c] = s_sm[c] * scl

    int tid = blockIdx.x * 256 + t;           // tid in [0, Nn/4)
    int n0  = tid * 4;
    int b   = n0 >> 18;                       // HWn = 2^18
    int hw  = n0 & (HWn - 1);
    const float4* p4 = (const float4*)(pred + (size_t)b * Cc * HWn + hw);

    int4 y4 = t4[tid];
    int ys[4] = {y4.x, y4.y, y4.z, y4.w};
    float smy[4];
    #pragma unroll
    for (int k = 0; k < 4; ++k) smy[k] = s_sm[ys[k]] * scl;

    // online logsumexp state per pixel
    float m[4]  = {-1e30f, -1e30f, -1e30f, -1e30f};
    float su[4] = {0.f, 0.f, 0.f, 0.f};
    float vy[4] = {0.f, 0.f, 0.f, 0.f};

    #pragma unroll
    for (int c = 0; c < Cc; ++c) {
        float4 x = p4[(size_t)c * (HWn / 4)];
        float xs[4] = {x.x, x.y, x.z, x.w};
        #pragma unroll
        for (int k = 0; k < 4; ++k) {
            bool  isy = (c == ys[k]);
            float val = fmaf(Sc, xs[k], isy ? -smy[k] : 0.0f);
            vy[k] = isy ? val : vy[k];
            float nm = fmaxf(m[k], val);
            su[k] = su[k] * __expf(m[k] - nm) + __expf(val - nm);
            m[k] = nm;
        }
    }

    float nll = 0.0f;
    #pragma unroll
    for (int k = 0; k < 4; ++k) nll += __logf(su[k]) + m[k] - vy[k];

    // wave (64-lane) reduce
    #pragma unroll
    for (int o = 32; o >= 1; o >>= 1) nll += __shfl_down(nll, o);

    int wave = t >> 6;
    int lane = t & 63;
    if (lane == 0) wsum[wave] = nll;
    __syncthreads();
    if (t == 0) {
        float bsum = wsum[0] + wsum[1] + wsum[2] + wsum[3];
        atomicAdd(acc, (double)bsum);
        __threadfence();                      // release: acc add visible before done inc
        int prev = atomicAdd(done, 1);
        if (prev == (int)gridDim.x - 1) {     // last block finalizes
            __threadfence();                  // acquire
            double total = atomicAdd(acc, 0.0);  // device-scope atomic read
            out[0] = (float)(total / (double)Nn);
        }
    }
}

extern "C" void kernel_launch(void* const* d_in, const int* in_sizes, int n_in,
                              void* d_out, int out_size, void* d_ws, size_t ws_size,
                              hipStream_t stream) {
    const float* pred   = (const float*)d_in[0];
    const int*   target = (const int*)d_in[1];
    float*       out    = (float*)d_out;

    char* ws = (char*)d_ws;
    int*    counts = (int*)(ws + WS_COUNTS);
    double* acc    = (double*)(ws + WS_ACC);
    int*    done   = (int*)(ws + WS_DONE);

    hipMemsetAsync(d_ws, 0, 256, stream);     // zero counts + acc + done

    const int nvec   = Nn / 4;                // 524288
    const int blocks = nvec / 256;            // 2048

    hist_kernel<<<blocks, 256, 0, stream>>>((const int4*)target, counts);
    loss_kernel<<<blocks, 256, 0, stream>>>(pred, (const int4*)target, counts,
                                            acc, done, out);
}